// Round 1
// baseline (1221.661 us; speedup 1.0000x reference)
//
#include <hip/hip_runtime.h>

#define NN 50000
#define NE 800000
#define DD 96
#define NEG 0.01f

// Phase 1: side[row] += val * ego[col] for each edge.
// 32 lanes per edge; lanes 0..23 each handle one float4 (96 floats).
__global__ __launch_bounds__(256) void scatter_kernel(
    const float* __restrict__ ego, const float* __restrict__ avals,
    const int* __restrict__ arows, const int* __restrict__ acols,
    float* __restrict__ side)
{
  int t = blockIdx.x * 256 + threadIdx.x;
  int e = t >> 5;
  int lane = t & 31;
  if (e >= NE) return;
  int row = arows[e];
  int col = acols[e];
  float v = avals[e];
  if (lane < 24) {
    const float4* src = (const float4*)(ego + (size_t)col * DD);
    float4 x = src[lane];
    float* dst = side + (size_t)row * DD + lane * 4;
    unsafeAtomicAdd(dst + 0, v * x.x);
    unsafeAtomicAdd(dst + 1, v * x.y);
    unsafeAtomicAdd(dst + 2, v * x.z);
    unsafeAtomicAdd(dst + 3, v * x.w);
  }
}

// Phase 2: out = lrelu((ego+side)@W1^T + b1) + lrelu((ego*side)@W2^T + b2)
// Block of 192 threads = 2 nodes/iter; thread t -> (node_local = t/96, j = t%96).
// W1,W2 staged transposed in LDS so inner-loop reads W[k*96+j] are j-fast
// (per-lane consecutive -> 2-way bank aliasing, free).
__global__ __launch_bounds__(192) void fuse_kernel(
    const float* __restrict__ ego, const float* __restrict__ side,
    const float* __restrict__ W1, const float* __restrict__ b1,
    const float* __restrict__ W2, const float* __restrict__ b2,
    float* __restrict__ out)
{
  __shared__ float W1t[DD * DD];
  __shared__ float W2t[DD * DD];
  __shared__ float b1s[DD], b2s[DD];
  __shared__ float xs[192], ys[192];

  int tid = threadIdx.x;
  for (int i = tid; i < DD * DD; i += 192) {
    int j = i / DD;
    int k = i - j * DD;
    W1t[k * DD + j] = W1[i];
    W2t[k * DD + j] = W2[i];
  }
  if (tid < DD) { b1s[tid] = b1[tid]; b2s[tid] = b2[tid]; }
  __syncthreads();

  int nl = tid / DD;       // 0 or 1
  int j  = tid - nl * DD;  // 0..95
  const int npairs = NN / 2;  // 25000 (N even)

  for (int p = blockIdx.x; p < npairs; p += gridDim.x) {
    int base = p * 192;
    // stage x = ego+side, y = ego*side for 2 nodes (192 contiguous floats)
    float e = ego[base + tid];
    float s = side[base + tid];
    xs[tid] = e + s;
    ys[tid] = e * s;
    __syncthreads();

    float a1 = b1s[j];
    float a2 = b2s[j];
    const float* xr = xs + nl * DD;
    const float* yr = ys + nl * DD;
#pragma unroll 16
    for (int k = 0; k < DD; ++k) {
      a1 += xr[k] * W1t[k * DD + j];
      a2 += yr[k] * W2t[k * DD + j];
    }
    float r1 = (a1 >= 0.f) ? a1 : NEG * a1;
    float r2 = (a2 >= 0.f) ? a2 : NEG * a2;
    __syncthreads();  // all reads of xs/ys done before next iter overwrites
    // node = 2p + nl; out index = base + nl*96 + j = base + tid
    out[base + tid] = r1 + r2;
  }
}

extern "C" void kernel_launch(void* const* d_in, const int* in_sizes, int n_in,
                              void* d_out, int out_size, void* d_ws, size_t ws_size,
                              hipStream_t stream) {
  const float* ego   = (const float*)d_in[0];
  const float* avals = (const float*)d_in[1];
  const float* W1    = (const float*)d_in[2];
  const float* b1    = (const float*)d_in[3];
  const float* W2    = (const float*)d_in[4];
  const float* b2    = (const float*)d_in[5];
  const int* arows   = (const int*)d_in[6];
  const int* acols   = (const int*)d_in[7];
  float* out = (float*)d_out;

  size_t side_bytes = (size_t)NN * DD * sizeof(float);
  // side accumulator: workspace if it fits, else accumulate in d_out
  // (phase 2 is safely in-place: each thread reads exactly the element it writes)
  float* side = (ws_size >= side_bytes) ? (float*)d_ws : out;

  hipMemsetAsync(side, 0, side_bytes, stream);

  long long nthreads = (long long)NE * 32;
  int blocks = (int)((nthreads + 255) / 256);
  scatter_kernel<<<blocks, 256, 0, stream>>>(ego, avals, arows, acols, side);

  fuse_kernel<<<1024, 192, 0, stream>>>(ego, side, W1, b1, W2, b2, out);
}

// Round 2
// 239.001 us; speedup vs baseline: 5.1115x; 5.1115x over previous
//
#include <hip/hip_runtime.h>

#define NN 50000
#define NE 800000
#define DD 96
#define NEG 0.01f
#define NB 196      // scan blocks: 196*256 = 50176 >= NN
#define NPI 32      // nodes per fuse3 block

static __device__ __forceinline__ float lrelu(float x) {
  return (x >= 0.f) ? x : NEG * x;
}

// ================= fallback (round-1) path =================
__global__ __launch_bounds__(256) void scatter_kernel(
    const float* __restrict__ ego, const float* __restrict__ avals,
    const int* __restrict__ arows, const int* __restrict__ acols,
    float* __restrict__ side)
{
  int t = blockIdx.x * 256 + threadIdx.x;
  int e = t >> 5;
  int lane = t & 31;
  if (e >= NE) return;
  int row = arows[e];
  int col = acols[e];
  float v = avals[e];
  if (lane < 24) {
    const float4* src = (const float4*)(ego + (size_t)col * DD);
    float4 x = src[lane];
    float* dst = side + (size_t)row * DD + lane * 4;
    unsafeAtomicAdd(dst + 0, v * x.x);
    unsafeAtomicAdd(dst + 1, v * x.y);
    unsafeAtomicAdd(dst + 2, v * x.z);
    unsafeAtomicAdd(dst + 3, v * x.w);
  }
}

__global__ __launch_bounds__(192) void fuse_kernel(
    const float* __restrict__ ego, const float* __restrict__ side,
    const float* __restrict__ W1, const float* __restrict__ b1,
    const float* __restrict__ W2, const float* __restrict__ b2,
    float* __restrict__ out)
{
  __shared__ float W1t[DD * DD];
  __shared__ float W2t[DD * DD];
  __shared__ float b1s[DD], b2s[DD];
  __shared__ float xs[192], ys[192];

  int tid = threadIdx.x;
  for (int i = tid; i < DD * DD; i += 192) {
    int j = i / DD;
    int k = i - j * DD;
    W1t[k * DD + j] = W1[i];
    W2t[k * DD + j] = W2[i];
  }
  if (tid < DD) { b1s[tid] = b1[tid]; b2s[tid] = b2[tid]; }
  __syncthreads();

  int nl = tid / DD;
  int j  = tid - nl * DD;
  const int npairs = NN / 2;

  for (int p = blockIdx.x; p < npairs; p += gridDim.x) {
    int base = p * 192;
    float e = ego[base + tid];
    float s = side[base + tid];
    xs[tid] = e + s;
    ys[tid] = e * s;
    __syncthreads();
    float a1 = b1s[j];
    float a2 = b2s[j];
    const float* xr = xs + nl * DD;
    const float* yr = ys + nl * DD;
#pragma unroll 16
    for (int k = 0; k < DD; ++k) {
      a1 += xr[k] * W1t[k * DD + j];
      a2 += yr[k] * W2t[k * DD + j];
    }
    float r1 = lrelu(a1);
    float r2 = lrelu(a2);
    __syncthreads();
    out[base + tid] = r1 + r2;
  }
}

// ================= CSR build =================
__global__ __launch_bounds__(256) void count_kernel(const int* __restrict__ rows,
                                                    int* __restrict__ cnt) {
  int e = blockIdx.x * 256 + threadIdx.x;
  if (e < NE) atomicAdd(&cnt[rows[e]], 1);
}

__global__ __launch_bounds__(256) void scan1_kernel(const int* __restrict__ cnt,
                                                    int* __restrict__ bsum) {
  __shared__ int s[256];
  int t = threadIdx.x, i = blockIdx.x * 256 + t;
  s[t] = (i < NN) ? cnt[i] : 0;
  __syncthreads();
  for (int off = 128; off > 0; off >>= 1) {
    if (t < off) s[t] += s[t + off];
    __syncthreads();
  }
  if (t == 0) bsum[blockIdx.x] = s[0];
}

__global__ __launch_bounds__(256) void scan2_kernel(const int* __restrict__ bsum,
                                                    int* __restrict__ bexcl) {
  __shared__ int s[256];
  int t = threadIdx.x;
  int v = (t < NB) ? bsum[t] : 0;
  s[t] = v;
  __syncthreads();
  for (int off = 1; off < 256; off <<= 1) {
    int add = (t >= off) ? s[t - off] : 0;
    __syncthreads();
    s[t] += add;
    __syncthreads();
  }
  if (t < NB) bexcl[t] = s[t] - v;
}

__global__ __launch_bounds__(256) void scan3_kernel(const int* __restrict__ cnt,
                                                    const int* __restrict__ bexcl,
                                                    int* __restrict__ row_start,
                                                    int* __restrict__ wptr) {
  __shared__ int s[256];
  int t = threadIdx.x, i = blockIdx.x * 256 + t;
  int v = (i < NN) ? cnt[i] : 0;
  s[t] = v;
  __syncthreads();
  for (int off = 1; off < 256; off <<= 1) {
    int add = (t >= off) ? s[t - off] : 0;
    __syncthreads();
    s[t] += add;
    __syncthreads();
  }
  int rs = bexcl[blockIdx.x] + s[t] - v;
  if (i < NN) { row_start[i] = rs; wptr[i] = rs; }
  if (i == NN) row_start[NN] = NE;
}

__global__ __launch_bounds__(256) void fill_kernel(const int* __restrict__ rows,
                                                   const int* __restrict__ cols,
                                                   const float* __restrict__ vals,
                                                   int* __restrict__ wptr,
                                                   int* __restrict__ cs,
                                                   float* __restrict__ vs) {
  int e = blockIdx.x * 256 + threadIdx.x;
  if (e >= NE) return;
  int r = rows[e];
  int p = atomicAdd(&wptr[r], 1);
  cs[p] = cols[e];
  vs[p] = vals[e];
}

__global__ __launch_bounds__(256) void transpose_kernel(const float* __restrict__ W1,
                                                        const float* __restrict__ W2,
                                                        float* __restrict__ W1t,
                                                        float* __restrict__ W2t) {
  int i = blockIdx.x * 256 + threadIdx.x;  // grid covers exactly DD*DD
  int j = i / DD, k = i - j * DD;
  W1t[k * DD + j] = W1[i];
  W2t[k * DD + j] = W2[i];
}

// ================= segment reduction: one wave per row =================
__global__ __launch_bounds__(256) void agg_kernel(const float* __restrict__ ego,
                                                  const int* __restrict__ row_start,
                                                  const int* __restrict__ cs,
                                                  const float* __restrict__ vs,
                                                  float* __restrict__ side) {
  int wid = threadIdx.x >> 6, lane = threadIdx.x & 63;
  int row = blockIdx.x * 4 + wid;
  if (row >= NN) return;
  int s = row_start[row], e = row_start[row + 1];
  float a0 = 0.f, a1 = 0.f;
  for (int p = s; p < e; ++p) {
    int c = cs[p];
    float v = vs[p];
    const float* eg = ego + (size_t)c * DD;
    a0 += v * eg[lane];
    if (lane < 32) a1 += v * eg[64 + lane];
  }
  float* dst = side + (size_t)row * DD;
  dst[lane] = a0;
  if (lane < 32) dst[64 + lane] = a1;
}

// ================= fused bi-interaction, register-tiled =================
// block 192 = 8 node-groups x 24 j-threads; 4 nodes x 4 j-cols per thread
__global__ __launch_bounds__(192) void fuse3_kernel(
    const float* __restrict__ ego, const float* __restrict__ side,
    const float* __restrict__ W1t, const float* __restrict__ W2t,
    const float* __restrict__ b1, const float* __restrict__ b2,
    float* __restrict__ out)
{
  __shared__ float xs[NPI * 97];
  __shared__ float ys[NPI * 97];
  int tid = threadIdx.x;
  int base96 = blockIdx.x * (NPI * DD);

  for (int i = tid; i < NPI * DD; i += 192) {
    int n = i / DD, k = i - n * DD;
    float e = 0.f, s = 0.f;
    if (base96 + i < NN * DD) {
      e = ego[base96 + i];
      s = side[base96 + i];
    }
    xs[n * 97 + k] = e + s;
    ys[n * 97 + k] = e * s;
  }
  __syncthreads();

  int ng = tid / 24;
  int jt = tid - ng * 24;
  int j0 = jt * 4;

  float4 bb1 = *(const float4*)(b1 + j0);
  float4 bb2 = *(const float4*)(b2 + j0);
  float4 acc1[4], acc2[4];
#pragma unroll
  for (int ni = 0; ni < 4; ++ni) { acc1[ni] = bb1; acc2[ni] = bb2; }

#pragma unroll 2
  for (int k = 0; k < DD; ++k) {
    float4 w1 = *(const float4*)(W1t + k * DD + j0);
    float4 w2 = *(const float4*)(W2t + k * DD + j0);
#pragma unroll
    for (int ni = 0; ni < 4; ++ni) {
      float xv = xs[(ng * 4 + ni) * 97 + k];
      float yv = ys[(ng * 4 + ni) * 97 + k];
      acc1[ni].x += xv * w1.x; acc1[ni].y += xv * w1.y;
      acc1[ni].z += xv * w1.z; acc1[ni].w += xv * w1.w;
      acc2[ni].x += yv * w2.x; acc2[ni].y += yv * w2.y;
      acc2[ni].z += yv * w2.z; acc2[ni].w += yv * w2.w;
    }
  }

#pragma unroll
  for (int ni = 0; ni < 4; ++ni) {
    int n = blockIdx.x * NPI + ng * 4 + ni;
    if (n < NN) {
      float4 r;
      r.x = lrelu(acc1[ni].x) + lrelu(acc2[ni].x);
      r.y = lrelu(acc1[ni].y) + lrelu(acc2[ni].y);
      r.z = lrelu(acc1[ni].z) + lrelu(acc2[ni].z);
      r.w = lrelu(acc1[ni].w) + lrelu(acc2[ni].w);
      *(float4*)(out + (size_t)n * DD + j0) = r;
    }
  }
}

// ================= launch =================
extern "C" void kernel_launch(void* const* d_in, const int* in_sizes, int n_in,
                              void* d_out, int out_size, void* d_ws, size_t ws_size,
                              hipStream_t stream) {
  const float* ego   = (const float*)d_in[0];
  const float* avals = (const float*)d_in[1];
  const float* W1    = (const float*)d_in[2];
  const float* b1    = (const float*)d_in[3];
  const float* W2    = (const float*)d_in[4];
  const float* b2    = (const float*)d_in[5];
  const int* arows   = (const int*)d_in[6];
  const int* acols   = (const int*)d_in[7];
  float* out = (float*)d_out;

  // ws layout (1KB-aligned bump)
  size_t off = 0;
  auto bump = [&](size_t bytes) {
    size_t o = off;
    off += (bytes + 1023) & ~(size_t)1023;
    return o;
  };
  char* ws = (char*)d_ws;
  size_t o_cnt  = bump((size_t)NN * 4);
  size_t o_rs   = bump((size_t)(NN + 1) * 4);
  size_t o_wp   = bump((size_t)NN * 4);
  size_t o_bs   = bump((size_t)NB * 4);
  size_t o_be   = bump((size_t)NB * 4);
  size_t o_cs   = bump((size_t)NE * 4);
  size_t o_vs   = bump((size_t)NE * 4);
  size_t o_w1t  = bump((size_t)DD * DD * 4);
  size_t o_w2t  = bump((size_t)DD * DD * 4);
  size_t o_side = bump((size_t)NN * DD * 4);
  size_t need = off;

  if (ws_size >= need) {
    int*   cnt  = (int*)(ws + o_cnt);
    int*   rs   = (int*)(ws + o_rs);
    int*   wp   = (int*)(ws + o_wp);
    int*   bs   = (int*)(ws + o_bs);
    int*   be   = (int*)(ws + o_be);
    int*   cs   = (int*)(ws + o_cs);
    float* vs   = (float*)(ws + o_vs);
    float* W1t  = (float*)(ws + o_w1t);
    float* W2t  = (float*)(ws + o_w2t);
    float* side = (float*)(ws + o_side);

    hipMemsetAsync(cnt, 0, (size_t)NN * 4, stream);
    count_kernel<<<NE / 256, 256, 0, stream>>>(arows, cnt);
    scan1_kernel<<<NB, 256, 0, stream>>>(cnt, bs);
    scan2_kernel<<<1, 256, 0, stream>>>(bs, be);
    scan3_kernel<<<NB, 256, 0, stream>>>(cnt, be, rs, wp);
    fill_kernel<<<NE / 256, 256, 0, stream>>>(arows, acols, avals, wp, cs, vs);
    transpose_kernel<<<(DD * DD) / 256, 256, 0, stream>>>(W1, W2, W1t, W2t);
    agg_kernel<<<(NN + 3) / 4, 256, 0, stream>>>(ego, rs, cs, vs, side);
    fuse3_kernel<<<(NN + NPI - 1) / NPI, 192, 0, stream>>>(
        ego, side, W1t, W2t, b1, b2, out);
  } else {
    // fallback: round-1 atomic path
    size_t side_bytes = (size_t)NN * DD * sizeof(float);
    float* side = (ws_size >= side_bytes) ? (float*)d_ws : out;
    hipMemsetAsync(side, 0, side_bytes, stream);
    long long nthreads = (long long)NE * 32;
    int blocks = (int)((nthreads + 255) / 256);
    scatter_kernel<<<blocks, 256, 0, stream>>>(ego, avals, arows, acols, side);
    fuse_kernel<<<1024, 192, 0, stream>>>(ego, side, W1, b1, W2, b2, out);
  }
}